// Round 11
// baseline (148.755 us; speedup 1.0000x reference)
//
#include <hip/hip_runtime.h>
#include <hip/hip_bf16.h>
#include <math.h>

#define FREQS 9
#define DATA_DIM 28
#define WIDTH 128
#define IN_DIM 82
#define HSTRIDE 40   // shorts per sample row in H stripe (80 B) -> ~2-way conflicts (free)
#define PEST 56      // f32 per W1_pe row in LDS (padded 54->56)

typedef float f32x4 __attribute__((ext_vector_type(4)));
typedef short s16x8 __attribute__((ext_vector_type(8)));

__device__ __forceinline__ short f2bf(float f) {
    unsigned u = __builtin_bit_cast(unsigned, f);
    u += 0x7fffu + ((u >> 16) & 1u);
    return (short)(u >> 16);
}

// native RNE pack: compiler lowers to v_cvt_pk_bf16_f32 (m240: don't hand-roll)
__device__ __forceinline__ unsigned pk2(float a, float b) {
    float2 t; t.x = a; t.y = b;
    __hip_bfloat162 h = __float22bfloat162_rn(t);
    unsigned r;
    __builtin_memcpy(&r, &h, sizeof(r));
    return r;
}

__device__ __forceinline__ float bf2f(unsigned u16v) {
    unsigned u = u16v << 16;
    return __builtin_bit_cast(float, u);
}

// ws: [0] nz counter, [1] flag, [64..64+B) cnt, [64+B..64+2B) roff,
// W1bf 128*32 bf16 (8KB), hpe B*128 f32 (4MB), packid P u32, preact P uint2.

__global__ void k_zero(int* ws) { ws[0] = 0; }

__global__ void k_count_bytes(const unsigned int* __restrict__ mw, int nwords, int* ws) {
    int tid = blockIdx.x * blockDim.x + threadIdx.x;
    int stride = gridDim.x * blockDim.x;
    int c = 0;
    for (int i = tid; i < nwords; i += stride) {
        unsigned int w = mw[i];
        c += ((w & 0xffu) != 0) + (((w >> 8) & 0xffu) != 0) +
             (((w >> 16) & 0xffu) != 0) + ((w >> 24) != 0);
    }
    __shared__ int red[256];
    red[threadIdx.x] = c;
    __syncthreads();
    for (int off = 128; off > 0; off >>= 1) {
        if (threadIdx.x < off) red[threadIdx.x] += red[threadIdx.x + off];
        __syncthreads();
    }
    if (threadIdx.x == 0) atomicAdd(&ws[0], red[0]);
}

__global__ void k_set_flag(int* ws, int P) { ws[1] = (ws[0] == P) ? 1 : 0; }

__global__ void k_ray_count(const void* __restrict__ maskp, const int* __restrict__ wsflag,
                            int* __restrict__ cnt, int N) {
    int b = blockIdx.x;
    int lane = threadIdx.x;
    int fl = wsflag[0];
    const unsigned char* m8 = (const unsigned char*)maskp;
    const int* m32 = (const int*)maskp;
    int base = 0;
    for (int t = 0; t < N / 64; ++t) {
        int n = t * 64 + lane;
        int mv = fl ? (int)m8[(size_t)b * N + n] : m32[(size_t)b * N + n];
        unsigned long long bal = __ballot(mv != 0);
        base += __popcll(bal);
    }
    if (lane == 0) cnt[b] = base;
}

__global__ void k_scan(const int* __restrict__ cnt, int* __restrict__ roff, int Bn) {
    __shared__ int sums[1024];
    int tid = threadIdx.x;
    int per = Bn / 1024;
    int loc[8];
    int s = 0;
    for (int i = 0; i < per; ++i) { loc[i] = s; s += cnt[tid * per + i]; }
    sums[tid] = s;
    __syncthreads();
    for (int off = 1; off < 1024; off <<= 1) {
        int t = sums[tid];
        int v = (tid >= off) ? sums[tid - off] : 0;
        __syncthreads();
        sums[tid] = t + v;
        __syncthreads();
    }
    int excl = sums[tid] - s;
    for (int i = 0; i < per; ++i) roff[tid * per + i] = excl + loc[i];
}

// packid[r] = (b<<16)|n for masked samples (ascending n); zero alpha for unmasked.
__global__ void k_packid(const void* __restrict__ maskp, const int* __restrict__ wsflag,
                         const int* __restrict__ roff, unsigned* __restrict__ packid,
                         float* __restrict__ out_alpha, int N) {
    int b = blockIdx.x;
    int lane = threadIdx.x;
    int fl = wsflag[0];
    const unsigned char* m8 = (const unsigned char*)maskp;
    const int* m32 = (const int*)maskp;
    int base = roff[b];
    for (int t = 0; t < N / 64; ++t) {
        int n = t * 64 + lane;
        int mv = fl ? (int)m8[(size_t)b * N + n] : m32[(size_t)b * N + n];
        bool m = (mv != 0);
        unsigned long long bal = __ballot(m);
        int rank = __popcll(bal & ((1ull << lane) - 1ull));
        if (m) packid[base + rank] = ((unsigned)b << 16) | (unsigned)n;
        else   out_alpha[(size_t)b * N + n] = 0.0f;
        base += __popcll(bal);
    }
}

// W1bf: data columns only (k=0..27), k=28..31 zero.
__global__ void k_prep(const float* __restrict__ W1, short* __restrict__ W1bf) {
    int tid = blockIdx.x * blockDim.x + threadIdx.x;
    if (tid < WIDTH * 32) {
        int n = tid / 32, k = tid - n * 32;
        W1bf[tid] = (k < DATA_DIM) ? f2bf(W1[n * IN_DIM + k]) : (short)0;
    }
}

// hpe[b][row] = b1[row] + sum_j W1[row][28+j] * pe_b[j]
__global__ __launch_bounds__(256) void k_hpe(
    const float* __restrict__ rays_d, const float* __restrict__ W1,
    const float* __restrict__ b1, float* __restrict__ hpe, int Bn)
{
    __shared__ __align__(16) float w1pe[WIDTH * PEST];   // 28 KB
    __shared__ __align__(16) float pe_s[4][PEST];

    int tid = threadIdx.x;
    for (int t = tid; t < WIDTH * PEST; t += 256) {
        int row = t / PEST, j = t - row * PEST;
        w1pe[t] = (j < 54) ? W1[row * IN_DIM + DATA_DIM + j] : 0.0f;
    }
    int wid = tid >> 6, lane = tid & 63;
    if (lane >= 54 && lane < PEST) pe_s[wid][lane] = 0.0f;
    __syncthreads();

    int raysPer = (Bn + gridDim.x - 1) / gridDim.x;
    for (int it = 0; it < raysPer; it += 4) {
        int b = blockIdx.x * raysPer + it + wid;
        if (b >= Bn) break;
        float dx = rays_d[b * 3 + 0], dy = rays_d[b * 3 + 1], dz = rays_d[b * 3 + 2];
        int idx = (lane < 54) ? lane : 0;
        int fb = idx / 6, t5 = idx - fb * 6;
        int ax = (t5 < 3) ? t5 : (t5 - 3);
        float dv = (ax == 0) ? dx : ((ax == 1) ? dy : dz);
        float ang = dv * (float)(1 << fb);
        float pev = (t5 < 3) ? sinf(ang) : cosf(ang);
        if (lane < 54) pe_s[wid][lane] = pev;

        #pragma unroll
        for (int rr = 0; rr < 2; ++rr) {
            int row = lane + 64 * rr;
            f32x4 s = {0.f, 0.f, 0.f, 0.f};
            #pragma unroll
            for (int j = 0; j < PEST; j += 4) {
                f32x4 wv = *reinterpret_cast<const f32x4*>(&w1pe[row * PEST + j]);
                f32x4 pv = *reinterpret_cast<const f32x4*>(&pe_s[wid][j]);
                s += wv * pv;
            }
            hpe[(size_t)b * WIDTH + row] = b1[row] + (s[0] + s[1]) + (s[2] + s[3]);
        }
    }
}

// ===== Phase 1: MLP over all packed samples. 1 batch per wave, no loops/barriers =====
// (256,4): cap 128 regs; measured arch 64 + acc <=64 fits. Guard: WRITE_SIZE.
__global__ __launch_bounds__(256, 4) void k_mlp(
    const float* __restrict__ data, const short* __restrict__ W1bf,
    const float* __restrict__ W2, const float* __restrict__ hpe,
    const unsigned* __restrict__ packid, uint2* __restrict__ preact, int P)
{
    int wid = threadIdx.x >> 6;
    int lane = threadIdx.x & 63;
    int g = lane >> 4, c = lane & 15;
    int q0 = blockIdx.x * 256 + wid * 64;

    __shared__ __align__(16) short hbuf[4][64 * HSTRIDE];   // 20 KB
    short* hb = &hbuf[wid][0];

    // per-mb sample ray ids + data fragments
    unsigned bs[4];
    s16x8 a0[4];
    #pragma unroll
    for (int mb = 0; mb < 4; ++mb) {
        int s = q0 + 16 * mb + c;
        s = (s < P) ? s : (P - 1);
        bs[mb] = packid[s] >> 16;
        const float* dr = data + (size_t)s * DATA_DIM;
        unsigned u0, u1, u2, u3;
        if (g < 3) {
            f32x4 lo = *reinterpret_cast<const f32x4*>(dr + 8 * g);
            f32x4 hi = *reinterpret_cast<const f32x4*>(dr + 8 * g + 4);
            u0 = pk2(lo[0], lo[1]); u1 = pk2(lo[2], lo[3]);
            u2 = pk2(hi[0], hi[1]); u3 = pk2(hi[2], hi[3]);
        } else {
            f32x4 lo = *reinterpret_cast<const f32x4*>(dr + 24);
            u0 = pk2(lo[0], lo[1]); u1 = pk2(lo[2], lo[3]);
            u2 = 0; u3 = 0;
        }
        uint4 uu; uu.x = u0; uu.y = u1; uu.z = u2; uu.w = u3;
        a0[mb] = __builtin_bit_cast(s16x8, uu);
    }

    // W2 A-fragments
    s16x8 w2f[4];
    #pragma unroll
    for (int ks = 0; ks < 4; ++ks) {
        if (c < 4) {
            const float* wp = W2 + c * WIDTH + 32 * ks + 8 * g;
            f32x4 u = *reinterpret_cast<const f32x4*>(wp);
            f32x4 v = *reinterpret_cast<const f32x4*>(wp + 4);
            #pragma unroll
            for (int j = 0; j < 4; ++j) {
                w2f[ks][j] = f2bf(u[j]);
                w2f[ks][4 + j] = f2bf(v[j]);
            }
        } else {
            #pragma unroll
            for (int j = 0; j < 8; ++j) w2f[ks][j] = 0;
        }
    }

    const s16x8* W1v = reinterpret_cast<const s16x8*>(W1bf);
    f32x4 D[4];
    #pragma unroll
    for (int t = 0; t < 4; ++t) D[t] = (f32x4){0.f, 0.f, 0.f, 0.f};

    #pragma unroll
    for (int ks = 0; ks < 4; ++ks) {
        #pragma unroll
        for (int h = 0; h < 2; ++h) {
            int nt = 2 * ks + h;
            s16x8 Bk0 = W1v[(16 * nt + c) * 4 + g];   // 8KB table, L1-resident

            f32x4 C0 = {0.f,0.f,0.f,0.f}, C1 = C0, C2 = C0, C3 = C0;
            C0 = __builtin_amdgcn_mfma_f32_16x16x32_bf16(Bk0, a0[0], C0, 0, 0, 0);
            C1 = __builtin_amdgcn_mfma_f32_16x16x32_bf16(Bk0, a0[1], C1, 0, 0, 0);
            C2 = __builtin_amdgcn_mfma_f32_16x16x32_bf16(Bk0, a0[2], C2, 0, 0, 0);
            C3 = __builtin_amdgcn_mfma_f32_16x16x32_bf16(Bk0, a0[3], C3, 0, 0, 0);

            // += hpe[b_sample][neuron 16nt+4g..+3], relu, bf16, H stripe
            f32x4 Cm[4] = {C0, C1, C2, C3};
            #pragma unroll
            for (int mb = 0; mb < 4; ++mb) {
                f32x4 hv = *reinterpret_cast<const f32x4*>(
                    hpe + (size_t)bs[mb] * WIDTH + 16 * nt + 4 * g);
                uint2 w;
                w.x = pk2(fmaxf(Cm[mb][0] + hv[0], 0.f), fmaxf(Cm[mb][1] + hv[1], 0.f));
                w.y = pk2(fmaxf(Cm[mb][2] + hv[2], 0.f), fmaxf(Cm[mb][3] + hv[3], 0.f));
                *reinterpret_cast<uint2*>(&hb[(16 * mb + c) * HSTRIDE + 16 * h + 4 * g]) = w;
            }
        }
        #pragma unroll
        for (int t = 0; t < 4; ++t) {
            s16x8 Bf = *reinterpret_cast<const s16x8*>(&hb[(16 * t + c) * HSTRIDE + 8 * g]);
            D[t] = __builtin_amdgcn_mfma_f32_16x16x32_bf16(w2f[ks], Bf, D[t], 0, 0, 0);
        }
    }

    // outputs 0..3 live on g==0 lanes: lane c holds sample q0+16t+c
    if (g == 0) {
        #pragma unroll
        for (int t = 0; t < 4; ++t) {
            int s = q0 + 16 * t + c;
            if (s < P) {
                uint2 w;
                w.x = pk2(D[t][0], D[t][1]);
                w.y = pk2(D[t][2], D[t][3]);
                preact[s] = w;
            }
        }
    }
}

// ===== Phase 2: per-ray composite (wave per ray) =====
__global__ __launch_bounds__(256) void k_comp(
    const float* __restrict__ rays_d, const float* __restrict__ intrs,
    const uint2* __restrict__ preact, const unsigned* __restrict__ packid,
    const int* __restrict__ cnt, const int* __restrict__ roff,
    const float* __restrict__ b2, float* __restrict__ out, int Bn, int N)
{
    int wid = threadIdx.x >> 6;
    int lane = threadIdx.x & 63;
    int b = blockIdx.x * 4 + wid;

    float* out_comp = out;
    float* out_alpha = out + (size_t)Bn * 3;

    int count = cnt[b];
    int poff = roff[b];

    float dx = rays_d[b * 3 + 0], dy = rays_d[b * 3 + 1], dz = rays_d[b * 3 + 2];
    float nrm = sqrtf(dx * dx + dy * dy + dz * dz);
    f32x4 b2v = *reinterpret_cast<const f32x4*>(b2);

    float T = 1.0f;
    float aR = 0.f, aG = 0.f, aB = 0.f, aA = 0.f;

    for (int r0 = 0; r0 < count; r0 += 64) {
        int r = r0 + lane;
        bool act = (r < count);
        int ri = poff + (act ? r : 0);
        uint2 pv = preact[ri];
        unsigned pos = packid[ri];
        int n = (int)(pos & 0xffffu);

        float p0 = bf2f(pv.x & 0xffffu) + b2v[0];
        float p1 = bf2f(pv.x >> 16)     + b2v[1];
        float p2 = bf2f(pv.y & 0xffffu) + b2v[2];
        float p3 = bf2f(pv.y >> 16)     + b2v[3];

        float density = fmaxf(p0, 0.0f);
        float dist = (intrs[(size_t)b * (N + 1) + n + 1] - intrs[(size_t)b * (N + 1) + n]) * nrm;
        float alpha = act ? (1.0f - expf(-density * dist)) : 0.0f;

        float fct = 1.0f - alpha + 1e-10f;
        float scan = fct;
        #pragma unroll
        for (int d = 1; d < 64; d <<= 1) {
            float o = __shfl_up(scan, d, 64);
            if (lane >= d) scan *= o;
        }
        float tot  = __shfl(scan, 63, 64);
        float excl = __shfl_up(scan, 1, 64);
        if (lane == 0) excl = 1.0f;

        float cum  = T * excl;
        float absl = alpha * cum;
        float sR = 1.0f / (1.0f + expf(-p1));
        float sG = 1.0f / (1.0f + expf(-p2));
        float sB = 1.0f / (1.0f + expf(-p3));
        aR = fmaf(absl, sR, aR);
        aG = fmaf(absl, sG, aG);
        aB = fmaf(absl, sB, aB);
        aA += absl;
        T *= tot;

        if (act) out_alpha[(size_t)b * N + n] = alpha;
    }

    #pragma unroll
    for (int d = 32; d > 0; d >>= 1) {
        aR += __shfl_down(aR, d, 64);
        aG += __shfl_down(aG, d, 64);
        aB += __shfl_down(aB, d, 64);
        aA += __shfl_down(aA, d, 64);
    }
    if (lane == 0) {
        out_comp[b * 3 + 0] = aR + (1.0f - aA);
        out_comp[b * 3 + 1] = aG + (1.0f - aA);
        out_comp[b * 3 + 2] = aB + (1.0f - aA);
    }
}

extern "C" void kernel_launch(void* const* d_in, const int* in_sizes, int n_in,
                              void* d_out, int out_size, void* d_ws, size_t ws_size,
                              hipStream_t stream) {
    const float* rays_d = (const float*)d_in[0];
    const float* intrs  = (const float*)d_in[1];
    const void*  maskp  = d_in[2];
    const float* data   = (const float*)d_in[3];
    const float* W1     = (const float*)d_in[4];
    const float* b1     = (const float*)d_in[5];
    const float* W2     = (const float*)d_in[6];
    const float* b2     = (const float*)d_in[7];
    float* out = (float*)d_out;

    int B = in_sizes[0] / 3;            // 8192
    int N = in_sizes[2] / B;            // 256
    int P = in_sizes[3] / DATA_DIM;     // packed sample count

    int* wsI        = (int*)d_ws;
    int* cnt        = wsI + 64;
    int* roff       = wsI + 64 + B;
    short* W1bf     = (short*)(wsI + 64 + 2 * B);         // 8 KB
    float* hpe      = (float*)(W1bf + WIDTH * 32);        // B*128 f32 = 4 MB
    unsigned* packid = (unsigned*)(hpe + (size_t)B * WIDTH);  // P u32
    uint2* preact   = (uint2*)(packid + ((P + 63) & ~63));    // P uint2

    float* out_alpha = out + (size_t)B * 3;

    k_zero<<<1, 1, 0, stream>>>(wsI);
    int nwords = (B * N) / 4;
    k_count_bytes<<<256, 256, 0, stream>>>((const unsigned int*)maskp, nwords, wsI);
    k_set_flag<<<1, 1, 0, stream>>>(wsI, P);
    k_ray_count<<<B, 64, 0, stream>>>(maskp, wsI + 1, cnt, N);
    k_scan<<<1, 1024, 0, stream>>>(cnt, roff, B);
    k_packid<<<B, 64, 0, stream>>>(maskp, wsI + 1, roff, packid, out_alpha, N);
    k_prep<<<(WIDTH * 32 + 255) / 256, 256, 0, stream>>>(W1, W1bf);
    k_hpe<<<256, 256, 0, stream>>>(rays_d, W1, b1, hpe, B);
    k_mlp<<<(P + 255) / 256, 256, 0, stream>>>(data, W1bf, W2, hpe, packid, preact, P);
    k_comp<<<B / 4, 256, 0, stream>>>(rays_d, intrs, preact, packid, cnt, roff, b2,
                                      out, B, N);
}

// Round 12
// 123.602 us; speedup vs baseline: 1.2035x; 1.2035x over previous
//
#include <hip/hip_runtime.h>
#include <hip/hip_bf16.h>
#include <math.h>

#define FREQS 9
#define DATA_DIM 28
#define WIDTH 128
#define IN_DIM 82
#define HSTRIDE 40   // shorts per sample row in H stripe (80 B) -> ~2-way conflicts (free)
#define PEST 56      // f32 per W1_pe row in LDS (padded 54->56)

typedef float f32x4 __attribute__((ext_vector_type(4)));
typedef short s16x8 __attribute__((ext_vector_type(8)));

__device__ __forceinline__ short f2bf(float f) {
    unsigned u = __builtin_bit_cast(unsigned, f);
    u += 0x7fffu + ((u >> 16) & 1u);
    return (short)(u >> 16);
}

// native RNE pack: compiler lowers to v_cvt_pk_bf16_f32 (m240: don't hand-roll)
__device__ __forceinline__ unsigned pk2(float a, float b) {
    float2 t; t.x = a; t.y = b;
    __hip_bfloat162 h = __float22bfloat162_rn(t);
    unsigned r;
    __builtin_memcpy(&r, &h, sizeof(r));
    return r;
}

__device__ __forceinline__ float bf2f(unsigned u16v) {
    unsigned u = u16v << 16;
    return __builtin_bit_cast(float, u);
}

// ws: [0] nz counter, [1] flag, [64..64+B) cnt, [64+B..64+2B) roff,
// W1bf 128*32 bf16 (8KB), hpe B*128 f32 (4MB), packid P u32, preact P uint2.

__global__ void k_zero(int* ws) { ws[0] = 0; }

__global__ void k_count_bytes(const unsigned int* __restrict__ mw, int nwords, int* ws) {
    int tid = blockIdx.x * blockDim.x + threadIdx.x;
    int stride = gridDim.x * blockDim.x;
    int c = 0;
    for (int i = tid; i < nwords; i += stride) {
        unsigned int w = mw[i];
        c += ((w & 0xffu) != 0) + (((w >> 8) & 0xffu) != 0) +
             (((w >> 16) & 0xffu) != 0) + ((w >> 24) != 0);
    }
    __shared__ int red[256];
    red[threadIdx.x] = c;
    __syncthreads();
    for (int off = 128; off > 0; off >>= 1) {
        if (threadIdx.x < off) red[threadIdx.x] += red[threadIdx.x + off];
        __syncthreads();
    }
    if (threadIdx.x == 0) atomicAdd(&ws[0], red[0]);
}

__global__ void k_set_flag(int* ws, int P) { ws[1] = (ws[0] == P) ? 1 : 0; }

__global__ void k_ray_count(const void* __restrict__ maskp, const int* __restrict__ wsflag,
                            int* __restrict__ cnt, int N) {
    int b = blockIdx.x;
    int lane = threadIdx.x;
    int fl = wsflag[0];
    const unsigned char* m8 = (const unsigned char*)maskp;
    const int* m32 = (const int*)maskp;
    int base = 0;
    for (int t = 0; t < N / 64; ++t) {
        int n = t * 64 + lane;
        int mv = fl ? (int)m8[(size_t)b * N + n] : m32[(size_t)b * N + n];
        unsigned long long bal = __ballot(mv != 0);
        base += __popcll(bal);
    }
    if (lane == 0) cnt[b] = base;
}

__global__ void k_scan(const int* __restrict__ cnt, int* __restrict__ roff, int Bn) {
    __shared__ int sums[1024];
    int tid = threadIdx.x;
    int per = Bn / 1024;
    int loc[8];
    int s = 0;
    for (int i = 0; i < per; ++i) { loc[i] = s; s += cnt[tid * per + i]; }
    sums[tid] = s;
    __syncthreads();
    for (int off = 1; off < 1024; off <<= 1) {
        int t = sums[tid];
        int v = (tid >= off) ? sums[tid - off] : 0;
        __syncthreads();
        sums[tid] = t + v;
        __syncthreads();
    }
    int excl = sums[tid] - s;
    for (int i = 0; i < per; ++i) roff[tid * per + i] = excl + loc[i];
}

// packid[r] = (b<<16)|n for masked samples (ascending n); zero alpha for unmasked.
__global__ void k_packid(const void* __restrict__ maskp, const int* __restrict__ wsflag,
                         const int* __restrict__ roff, unsigned* __restrict__ packid,
                         float* __restrict__ out_alpha, int N) {
    int b = blockIdx.x;
    int lane = threadIdx.x;
    int fl = wsflag[0];
    const unsigned char* m8 = (const unsigned char*)maskp;
    const int* m32 = (const int*)maskp;
    int base = roff[b];
    for (int t = 0; t < N / 64; ++t) {
        int n = t * 64 + lane;
        int mv = fl ? (int)m8[(size_t)b * N + n] : m32[(size_t)b * N + n];
        bool m = (mv != 0);
        unsigned long long bal = __ballot(m);
        int rank = __popcll(bal & ((1ull << lane) - 1ull));
        if (m) packid[base + rank] = ((unsigned)b << 16) | (unsigned)n;
        else   out_alpha[(size_t)b * N + n] = 0.0f;
        base += __popcll(bal);
    }
}

// W1bf: data columns only (k=0..27), k=28..31 zero.
__global__ void k_prep(const float* __restrict__ W1, short* __restrict__ W1bf) {
    int tid = blockIdx.x * blockDim.x + threadIdx.x;
    if (tid < WIDTH * 32) {
        int n = tid / 32, k = tid - n * 32;
        W1bf[tid] = (k < DATA_DIM) ? f2bf(W1[n * IN_DIM + k]) : (short)0;
    }
}

// hpe[b][row] = b1[row] + sum_j W1[row][28+j] * pe_b[j]
__global__ __launch_bounds__(256) void k_hpe(
    const float* __restrict__ rays_d, const float* __restrict__ W1,
    const float* __restrict__ b1, float* __restrict__ hpe, int Bn)
{
    __shared__ __align__(16) float w1pe[WIDTH * PEST];   // 28 KB
    __shared__ __align__(16) float pe_s[4][PEST];

    int tid = threadIdx.x;
    for (int t = tid; t < WIDTH * PEST; t += 256) {
        int row = t / PEST, j = t - row * PEST;
        w1pe[t] = (j < 54) ? W1[row * IN_DIM + DATA_DIM + j] : 0.0f;
    }
    int wid = tid >> 6, lane = tid & 63;
    if (lane >= 54 && lane < PEST) pe_s[wid][lane] = 0.0f;
    __syncthreads();

    int raysPer = (Bn + gridDim.x - 1) / gridDim.x;
    for (int it = 0; it < raysPer; it += 4) {
        int b = blockIdx.x * raysPer + it + wid;
        if (b >= Bn) break;
        float dx = rays_d[b * 3 + 0], dy = rays_d[b * 3 + 1], dz = rays_d[b * 3 + 2];
        int idx = (lane < 54) ? lane : 0;
        int fb = idx / 6, t5 = idx - fb * 6;
        int ax = (t5 < 3) ? t5 : (t5 - 3);
        float dv = (ax == 0) ? dx : ((ax == 1) ? dy : dz);
        float ang = dv * (float)(1 << fb);
        float pev = (t5 < 3) ? sinf(ang) : cosf(ang);
        if (lane < 54) pe_s[wid][lane] = pev;

        #pragma unroll
        for (int rr = 0; rr < 2; ++rr) {
            int row = lane + 64 * rr;
            f32x4 s = {0.f, 0.f, 0.f, 0.f};
            #pragma unroll
            for (int j = 0; j < PEST; j += 4) {
                f32x4 wv = *reinterpret_cast<const f32x4*>(&w1pe[row * PEST + j]);
                f32x4 pv = *reinterpret_cast<const f32x4*>(&pe_s[wid][j]);
                s += wv * pv;
            }
            hpe[(size_t)b * WIDTH + row] = b1[row] + (s[0] + s[1]) + (s[2] + s[3]);
        }
    }
}

// ===== Phase 1: MLP over all packed samples. 1 batch per wave, no loops/barriers =====
// (256,3): the proven no-spill point (R10: VGPR 64, WRITE 8MB). R11's (256,4)
// spilled (WRITE 121MB) — cap 128 < live arch+acc. Only pk2 differs from R10.
__global__ __launch_bounds__(256, 3) void k_mlp(
    const float* __restrict__ data, const short* __restrict__ W1bf,
    const float* __restrict__ W2, const float* __restrict__ hpe,
    const unsigned* __restrict__ packid, uint2* __restrict__ preact, int P)
{
    int wid = threadIdx.x >> 6;
    int lane = threadIdx.x & 63;
    int g = lane >> 4, c = lane & 15;
    int q0 = blockIdx.x * 256 + wid * 64;

    __shared__ __align__(16) short hbuf[4][64 * HSTRIDE];   // 20 KB
    short* hb = &hbuf[wid][0];

    // per-mb sample ray ids + data fragments
    unsigned bs[4];
    s16x8 a0[4];
    #pragma unroll
    for (int mb = 0; mb < 4; ++mb) {
        int s = q0 + 16 * mb + c;
        s = (s < P) ? s : (P - 1);
        bs[mb] = packid[s] >> 16;
        const float* dr = data + (size_t)s * DATA_DIM;
        unsigned u0, u1, u2, u3;
        if (g < 3) {
            f32x4 lo = *reinterpret_cast<const f32x4*>(dr + 8 * g);
            f32x4 hi = *reinterpret_cast<const f32x4*>(dr + 8 * g + 4);
            u0 = pk2(lo[0], lo[1]); u1 = pk2(lo[2], lo[3]);
            u2 = pk2(hi[0], hi[1]); u3 = pk2(hi[2], hi[3]);
        } else {
            f32x4 lo = *reinterpret_cast<const f32x4*>(dr + 24);
            u0 = pk2(lo[0], lo[1]); u1 = pk2(lo[2], lo[3]);
            u2 = 0; u3 = 0;
        }
        uint4 uu; uu.x = u0; uu.y = u1; uu.z = u2; uu.w = u3;
        a0[mb] = __builtin_bit_cast(s16x8, uu);
    }

    // W2 A-fragments
    s16x8 w2f[4];
    #pragma unroll
    for (int ks = 0; ks < 4; ++ks) {
        if (c < 4) {
            const float* wp = W2 + c * WIDTH + 32 * ks + 8 * g;
            f32x4 u = *reinterpret_cast<const f32x4*>(wp);
            f32x4 v = *reinterpret_cast<const f32x4*>(wp + 4);
            #pragma unroll
            for (int j = 0; j < 4; ++j) {
                w2f[ks][j] = f2bf(u[j]);
                w2f[ks][4 + j] = f2bf(v[j]);
            }
        } else {
            #pragma unroll
            for (int j = 0; j < 8; ++j) w2f[ks][j] = 0;
        }
    }

    const s16x8* W1v = reinterpret_cast<const s16x8*>(W1bf);
    f32x4 D[4];
    #pragma unroll
    for (int t = 0; t < 4; ++t) D[t] = (f32x4){0.f, 0.f, 0.f, 0.f};

    #pragma unroll
    for (int ks = 0; ks < 4; ++ks) {
        #pragma unroll
        for (int h = 0; h < 2; ++h) {
            int nt = 2 * ks + h;
            s16x8 Bk0 = W1v[(16 * nt + c) * 4 + g];   // 8KB table, L1-resident

            f32x4 C0 = {0.f,0.f,0.f,0.f}, C1 = C0, C2 = C0, C3 = C0;
            C0 = __builtin_amdgcn_mfma_f32_16x16x32_bf16(Bk0, a0[0], C0, 0, 0, 0);
            C1 = __builtin_amdgcn_mfma_f32_16x16x32_bf16(Bk0, a0[1], C1, 0, 0, 0);
            C2 = __builtin_amdgcn_mfma_f32_16x16x32_bf16(Bk0, a0[2], C2, 0, 0, 0);
            C3 = __builtin_amdgcn_mfma_f32_16x16x32_bf16(Bk0, a0[3], C3, 0, 0, 0);

            // += hpe[b_sample][neuron 16nt+4g..+3], relu, bf16, H stripe
            f32x4 Cm[4] = {C0, C1, C2, C3};
            #pragma unroll
            for (int mb = 0; mb < 4; ++mb) {
                f32x4 hv = *reinterpret_cast<const f32x4*>(
                    hpe + (size_t)bs[mb] * WIDTH + 16 * nt + 4 * g);
                uint2 w;
                w.x = pk2(fmaxf(Cm[mb][0] + hv[0], 0.f), fmaxf(Cm[mb][1] + hv[1], 0.f));
                w.y = pk2(fmaxf(Cm[mb][2] + hv[2], 0.f), fmaxf(Cm[mb][3] + hv[3], 0.f));
                *reinterpret_cast<uint2*>(&hb[(16 * mb + c) * HSTRIDE + 16 * h + 4 * g]) = w;
            }
        }
        #pragma unroll
        for (int t = 0; t < 4; ++t) {
            s16x8 Bf = *reinterpret_cast<const s16x8*>(&hb[(16 * t + c) * HSTRIDE + 8 * g]);
            D[t] = __builtin_amdgcn_mfma_f32_16x16x32_bf16(w2f[ks], Bf, D[t], 0, 0, 0);
        }
    }

    // outputs 0..3 live on g==0 lanes: lane c holds sample q0+16t+c
    if (g == 0) {
        #pragma unroll
        for (int t = 0; t < 4; ++t) {
            int s = q0 + 16 * t + c;
            if (s < P) {
                uint2 w;
                w.x = pk2(D[t][0], D[t][1]);
                w.y = pk2(D[t][2], D[t][3]);
                preact[s] = w;
            }
        }
    }
}

// ===== Phase 2: per-ray composite (wave per ray) =====
__global__ __launch_bounds__(256) void k_comp(
    const float* __restrict__ rays_d, const float* __restrict__ intrs,
    const uint2* __restrict__ preact, const unsigned* __restrict__ packid,
    const int* __restrict__ cnt, const int* __restrict__ roff,
    const float* __restrict__ b2, float* __restrict__ out, int Bn, int N)
{
    int wid = threadIdx.x >> 6;
    int lane = threadIdx.x & 63;
    int b = blockIdx.x * 4 + wid;

    float* out_comp = out;
    float* out_alpha = out + (size_t)Bn * 3;

    int count = cnt[b];
    int poff = roff[b];

    float dx = rays_d[b * 3 + 0], dy = rays_d[b * 3 + 1], dz = rays_d[b * 3 + 2];
    float nrm = sqrtf(dx * dx + dy * dy + dz * dz);
    f32x4 b2v = *reinterpret_cast<const f32x4*>(b2);

    float T = 1.0f;
    float aR = 0.f, aG = 0.f, aB = 0.f, aA = 0.f;

    for (int r0 = 0; r0 < count; r0 += 64) {
        int r = r0 + lane;
        bool act = (r < count);
        int ri = poff + (act ? r : 0);
        uint2 pv = preact[ri];
        unsigned pos = packid[ri];
        int n = (int)(pos & 0xffffu);

        float p0 = bf2f(pv.x & 0xffffu) + b2v[0];
        float p1 = bf2f(pv.x >> 16)     + b2v[1];
        float p2 = bf2f(pv.y & 0xffffu) + b2v[2];
        float p3 = bf2f(pv.y >> 16)     + b2v[3];

        float density = fmaxf(p0, 0.0f);
        float dist = (intrs[(size_t)b * (N + 1) + n + 1] - intrs[(size_t)b * (N + 1) + n]) * nrm;
        float alpha = act ? (1.0f - expf(-density * dist)) : 0.0f;

        float fct = 1.0f - alpha + 1e-10f;
        float scan = fct;
        #pragma unroll
        for (int d = 1; d < 64; d <<= 1) {
            float o = __shfl_up(scan, d, 64);
            if (lane >= d) scan *= o;
        }
        float tot  = __shfl(scan, 63, 64);
        float excl = __shfl_up(scan, 1, 64);
        if (lane == 0) excl = 1.0f;

        float cum  = T * excl;
        float absl = alpha * cum;
        float sR = 1.0f / (1.0f + expf(-p1));
        float sG = 1.0f / (1.0f + expf(-p2));
        float sB = 1.0f / (1.0f + expf(-p3));
        aR = fmaf(absl, sR, aR);
        aG = fmaf(absl, sG, aG);
        aB = fmaf(absl, sB, aB);
        aA += absl;
        T *= tot;

        if (act) out_alpha[(size_t)b * N + n] = alpha;
    }

    #pragma unroll
    for (int d = 32; d > 0; d >>= 1) {
        aR += __shfl_down(aR, d, 64);
        aG += __shfl_down(aG, d, 64);
        aB += __shfl_down(aB, d, 64);
        aA += __shfl_down(aA, d, 64);
    }
    if (lane == 0) {
        out_comp[b * 3 + 0] = aR + (1.0f - aA);
        out_comp[b * 3 + 1] = aG + (1.0f - aA);
        out_comp[b * 3 + 2] = aB + (1.0f - aA);
    }
}

extern "C" void kernel_launch(void* const* d_in, const int* in_sizes, int n_in,
                              void* d_out, int out_size, void* d_ws, size_t ws_size,
                              hipStream_t stream) {
    const float* rays_d = (const float*)d_in[0];
    const float* intrs  = (const float*)d_in[1];
    const void*  maskp  = d_in[2];
    const float* data   = (const float*)d_in[3];
    const float* W1     = (const float*)d_in[4];
    const float* b1     = (const float*)d_in[5];
    const float* W2     = (const float*)d_in[6];
    const float* b2     = (const float*)d_in[7];
    float* out = (float*)d_out;

    int B = in_sizes[0] / 3;            // 8192
    int N = in_sizes[2] / B;            // 256
    int P = in_sizes[3] / DATA_DIM;     // packed sample count

    int* wsI        = (int*)d_ws;
    int* cnt        = wsI + 64;
    int* roff       = wsI + 64 + B;
    short* W1bf     = (short*)(wsI + 64 + 2 * B);         // 8 KB
    float* hpe      = (float*)(W1bf + WIDTH * 32);        // B*128 f32 = 4 MB
    unsigned* packid = (unsigned*)(hpe + (size_t)B * WIDTH);  // P u32
    uint2* preact   = (uint2*)(packid + ((P + 63) & ~63));    // P uint2

    float* out_alpha = out + (size_t)B * 3;

    k_zero<<<1, 1, 0, stream>>>(wsI);
    int nwords = (B * N) / 4;
    k_count_bytes<<<256, 256, 0, stream>>>((const unsigned int*)maskp, nwords, wsI);
    k_set_flag<<<1, 1, 0, stream>>>(wsI, P);
    k_ray_count<<<B, 64, 0, stream>>>(maskp, wsI + 1, cnt, N);
    k_scan<<<1, 1024, 0, stream>>>(cnt, roff, B);
    k_packid<<<B, 64, 0, stream>>>(maskp, wsI + 1, roff, packid, out_alpha, N);
    k_prep<<<(WIDTH * 32 + 255) / 256, 256, 0, stream>>>(W1, W1bf);
    k_hpe<<<256, 256, 0, stream>>>(rays_d, W1, b1, hpe, B);
    k_mlp<<<(P + 255) / 256, 256, 0, stream>>>(data, W1bf, W2, hpe, packid, preact, P);
    k_comp<<<B / 4, 256, 0, stream>>>(rays_d, intrs, preact, packid, cnt, roff, b2,
                                      out, B, N);
}

// Round 14
// 116.654 us; speedup vs baseline: 1.2752x; 1.0596x over previous
//
#include <hip/hip_runtime.h>
#include <hip/hip_bf16.h>
#include <math.h>

#define FREQS 9
#define DATA_DIM 28
#define WIDTH 128
#define IN_DIM 82
#define HST2 72      // shorts per sample row in 64-neuron H stripe (144 B) -> ~2-way
#define PEST 56      // f32 per W1_pe row in LDS (padded 54->56)

typedef float f32x4 __attribute__((ext_vector_type(4)));
typedef short s16x8 __attribute__((ext_vector_type(8)));

__device__ __forceinline__ short f2bf(float f) {
    unsigned u = __builtin_bit_cast(unsigned, f);
    u += 0x7fffu + ((u >> 16) & 1u);
    return (short)(u >> 16);
}

// native RNE pack -> v_cvt_pk_bf16_f32 (m240: don't hand-roll)
__device__ __forceinline__ unsigned pk2(float a, float b) {
    float2 t; t.x = a; t.y = b;
    __hip_bfloat162 h = __float22bfloat162_rn(t);
    unsigned r;
    __builtin_memcpy(&r, &h, sizeof(r));
    return r;
}

__device__ __forceinline__ float bf2f(unsigned u16v) {
    unsigned u = u16v << 16;
    return __builtin_bit_cast(float, u);
}

// ws: [0] nz counter, [1] flag, [64..64+B) cnt, [64+B..64+2B) roff,
// W1bf 128*32 bf16 (8KB), hpe B*128 f32 (4MB), packid P u32, preact P uint2.
// NOTE (R13 lesson): packed order MUST be the reference's flatnonzero order
// (b-major exclusive scan) — data rows are indexed by it. No atomic packing.

__global__ void k_zero(int* ws) { ws[0] = 0; }

__global__ void k_count_bytes(const unsigned int* __restrict__ mw, int nwords, int* ws) {
    int tid = blockIdx.x * blockDim.x + threadIdx.x;
    int stride = gridDim.x * blockDim.x;
    int c = 0;
    for (int i = tid; i < nwords; i += stride) {
        unsigned int w = mw[i];
        c += ((w & 0xffu) != 0) + (((w >> 8) & 0xffu) != 0) +
             (((w >> 16) & 0xffu) != 0) + ((w >> 24) != 0);
    }
    __shared__ int red[256];
    red[threadIdx.x] = c;
    __syncthreads();
    for (int off = 128; off > 0; off >>= 1) {
        if (threadIdx.x < off) red[threadIdx.x] += red[threadIdx.x + off];
        __syncthreads();
    }
    if (threadIdx.x == 0) atomicAdd(&ws[0], red[0]);
}

__global__ void k_set_flag(int* ws, int P) { ws[1] = (ws[0] == P) ? 1 : 0; }

__global__ void k_ray_count(const void* __restrict__ maskp, const int* __restrict__ wsflag,
                            int* __restrict__ cnt, int N) {
    int b = blockIdx.x;
    int lane = threadIdx.x;
    int fl = wsflag[0];
    const unsigned char* m8 = (const unsigned char*)maskp;
    const int* m32 = (const int*)maskp;
    int base = 0;
    for (int t = 0; t < N / 64; ++t) {
        int n = t * 64 + lane;
        int mv = fl ? (int)m8[(size_t)b * N + n] : m32[(size_t)b * N + n];
        unsigned long long bal = __ballot(mv != 0);
        base += __popcll(bal);
    }
    if (lane == 0) cnt[b] = base;
}

__global__ void k_scan(const int* __restrict__ cnt, int* __restrict__ roff, int Bn) {
    __shared__ int sums[1024];
    int tid = threadIdx.x;
    int per = Bn / 1024;
    int loc[8];
    int s = 0;
    for (int i = 0; i < per; ++i) { loc[i] = s; s += cnt[tid * per + i]; }
    sums[tid] = s;
    __syncthreads();
    for (int off = 1; off < 1024; off <<= 1) {
        int t = sums[tid];
        int v = (tid >= off) ? sums[tid - off] : 0;
        __syncthreads();
        sums[tid] = t + v;
        __syncthreads();
    }
    int excl = sums[tid] - s;
    for (int i = 0; i < per; ++i) roff[tid * per + i] = excl + loc[i];
}

// packid[r] = (b<<16)|n for masked samples (ascending n); zero alpha for unmasked.
__global__ void k_packid(const void* __restrict__ maskp, const int* __restrict__ wsflag,
                         const int* __restrict__ roff, unsigned* __restrict__ packid,
                         float* __restrict__ out_alpha, int N) {
    int b = blockIdx.x;
    int lane = threadIdx.x;
    int fl = wsflag[0];
    const unsigned char* m8 = (const unsigned char*)maskp;
    const int* m32 = (const int*)maskp;
    int base = roff[b];
    for (int t = 0; t < N / 64; ++t) {
        int n = t * 64 + lane;
        int mv = fl ? (int)m8[(size_t)b * N + n] : m32[(size_t)b * N + n];
        bool m = (mv != 0);
        unsigned long long bal = __ballot(m);
        int rank = __popcll(bal & ((1ull << lane) - 1ull));
        if (m) packid[base + rank] = ((unsigned)b << 16) | (unsigned)n;
        else   out_alpha[(size_t)b * N + n] = 0.0f;
        base += __popcll(bal);
    }
}

// W1bf: data columns only (k=0..27), k=28..31 zero.
__global__ void k_prep(const float* __restrict__ W1, short* __restrict__ W1bf) {
    int tid = blockIdx.x * blockDim.x + threadIdx.x;
    if (tid < WIDTH * 32) {
        int n = tid / 32, k = tid - n * 32;
        W1bf[tid] = (k < DATA_DIM) ? f2bf(W1[n * IN_DIM + k]) : (short)0;
    }
}

// hpe[b][row] = b1[row] + sum_j W1[row][28+j] * pe_b[j]
__global__ __launch_bounds__(256) void k_hpe(
    const float* __restrict__ rays_d, const float* __restrict__ W1,
    const float* __restrict__ b1, float* __restrict__ hpe, int Bn)
{
    __shared__ __align__(16) float w1pe[WIDTH * PEST];   // 28 KB
    __shared__ __align__(16) float pe_s[4][PEST];

    int tid = threadIdx.x;
    for (int t = tid; t < WIDTH * PEST; t += 256) {
        int row = t / PEST, j = t - row * PEST;
        w1pe[t] = (j < 54) ? W1[row * IN_DIM + DATA_DIM + j] : 0.0f;
    }
    int wid = tid >> 6, lane = tid & 63;
    if (lane >= 54 && lane < PEST) pe_s[wid][lane] = 0.0f;
    __syncthreads();

    int raysPer = (Bn + gridDim.x - 1) / gridDim.x;
    for (int it = 0; it < raysPer; it += 4) {
        int b = blockIdx.x * raysPer + it + wid;
        if (b >= Bn) break;
        float dx = rays_d[b * 3 + 0], dy = rays_d[b * 3 + 1], dz = rays_d[b * 3 + 2];
        int idx = (lane < 54) ? lane : 0;
        int fb = idx / 6, t5 = idx - fb * 6;
        int ax = (t5 < 3) ? t5 : (t5 - 3);
        float dv = (ax == 0) ? dx : ((ax == 1) ? dy : dz);
        float ang = dv * (float)(1 << fb);
        float pev = (t5 < 3) ? sinf(ang) : cosf(ang);
        if (lane < 54) pe_s[wid][lane] = pev;

        #pragma unroll
        for (int rr = 0; rr < 2; ++rr) {
            int row = lane + 64 * rr;
            f32x4 s = {0.f, 0.f, 0.f, 0.f};
            #pragma unroll
            for (int j = 0; j < PEST; j += 4) {
                f32x4 wv = *reinterpret_cast<const f32x4*>(&w1pe[row * PEST + j]);
                f32x4 pv = *reinterpret_cast<const f32x4*>(&pe_s[wid][j]);
                s += wv * pv;
            }
            hpe[(size_t)b * WIDTH + row] = b1[row] + (s[0] + s[1]) + (s[2] + s[3]);
        }
    }
}

// ===== Phase 1: MLP over packed samples; 2 macro-K-steps; XCD-swizzled blocks =====
// (256,3): proven no-spill point (R10/R12). R7/R11: anything tighter spills.
__global__ __launch_bounds__(256, 3) void k_mlp(
    const float* __restrict__ data, const short* __restrict__ W1bf,
    const float* __restrict__ W2, const float* __restrict__ hpe,
    const unsigned* __restrict__ packid, uint2* __restrict__ preact, int P)
{
    int wid = threadIdx.x >> 6;
    int lane = threadIdx.x & 63;
    int g = lane >> 4, c = lane & 15;

    // XCD-aware bijective swizzle (T1, m204): chunk grid across 8 XCDs for hpe L2 locality.
    int nwg = gridDim.x;
    int bid = blockIdx.x;
    if (nwg >= 8) {
        int q = nwg / 8, r = nwg % 8;
        int xcd = bid % 8, off = bid / 8;
        bid = (xcd < r ? xcd * (q + 1) : r * (q + 1) + (xcd - r) * q) + off;
    }
    int q0 = bid * 256 + wid * 64;

    __shared__ __align__(16) short hbuf[4][64 * HST2];   // 36.9 KB
    short* hb = &hbuf[wid][0];

    // per-mb sample ray ids + data fragments
    unsigned bs[4];
    s16x8 a0[4];
    #pragma unroll
    for (int mb = 0; mb < 4; ++mb) {
        int s = q0 + 16 * mb + c;
        s = (s < P) ? s : (P - 1);
        bs[mb] = packid[s] >> 16;
        const float* dr = data + (size_t)s * DATA_DIM;
        unsigned u0, u1, u2, u3;
        if (g < 3) {
            f32x4 lo = *reinterpret_cast<const f32x4*>(dr + 8 * g);
            f32x4 hi = *reinterpret_cast<const f32x4*>(dr + 8 * g + 4);
            u0 = pk2(lo[0], lo[1]); u1 = pk2(lo[2], lo[3]);
            u2 = pk2(hi[0], hi[1]); u3 = pk2(hi[2], hi[3]);
        } else {
            f32x4 lo = *reinterpret_cast<const f32x4*>(dr + 24);
            u0 = pk2(lo[0], lo[1]); u1 = pk2(lo[2], lo[3]);
            u2 = 0; u3 = 0;
        }
        uint4 uu; uu.x = u0; uu.y = u1; uu.z = u2; uu.w = u3;
        a0[mb] = __builtin_bit_cast(s16x8, uu);
    }

    // W2 A-fragments
    s16x8 w2f[4];
    #pragma unroll
    for (int ks = 0; ks < 4; ++ks) {
        if (c < 4) {
            const float* wp = W2 + c * WIDTH + 32 * ks + 8 * g;
            f32x4 u = *reinterpret_cast<const f32x4*>(wp);
            f32x4 v = *reinterpret_cast<const f32x4*>(wp + 4);
            #pragma unroll
            for (int j = 0; j < 4; ++j) {
                w2f[ks][j] = f2bf(u[j]);
                w2f[ks][4 + j] = f2bf(v[j]);
            }
        } else {
            #pragma unroll
            for (int j = 0; j < 8; ++j) w2f[ks][j] = 0;
        }
    }

    const s16x8* W1v = reinterpret_cast<const s16x8*>(W1bf);
    f32x4 D[4];
    #pragma unroll
    for (int t = 0; t < 4; ++t) D[t] = (f32x4){0.f, 0.f, 0.f, 0.f};

    #pragma unroll
    for (int ms = 0; ms < 2; ++ms) {
        // layer-1 for 64 neurons (4 nt iterations) -> H stripe cols 0..63
        #pragma unroll
        for (int hh = 0; hh < 4; ++hh) {
            int nt = 4 * ms + hh;
            s16x8 Bk0 = W1v[(16 * nt + c) * 4 + g];   // 8KB table, L1-resident

            f32x4 C0 = {0.f,0.f,0.f,0.f}, C1 = C0, C2 = C0, C3 = C0;
            C0 = __builtin_amdgcn_mfma_f32_16x16x32_bf16(Bk0, a0[0], C0, 0, 0, 0);
            C1 = __builtin_amdgcn_mfma_f32_16x16x32_bf16(Bk0, a0[1], C1, 0, 0, 0);
            C2 = __builtin_amdgcn_mfma_f32_16x16x32_bf16(Bk0, a0[2], C2, 0, 0, 0);
            C3 = __builtin_amdgcn_mfma_f32_16x16x32_bf16(Bk0, a0[3], C3, 0, 0, 0);

            f32x4 Cm[4] = {C0, C1, C2, C3};
            #pragma unroll
            for (int mb = 0; mb < 4; ++mb) {
                f32x4 hv = *reinterpret_cast<const f32x4*>(
                    hpe + (size_t)bs[mb] * WIDTH + 16 * nt + 4 * g);
                uint2 w;
                w.x = pk2(fmaxf(Cm[mb][0] + hv[0], 0.f), fmaxf(Cm[mb][1] + hv[1], 0.f));
                w.y = pk2(fmaxf(Cm[mb][2] + hv[2], 0.f), fmaxf(Cm[mb][3] + hv[3], 0.f));
                *reinterpret_cast<uint2*>(&hb[(16 * mb + c) * HST2 + 16 * hh + 4 * g]) = w;
            }
        }
        // single LDS turnaround, then 8 layer-2 MFMAs over the 64-neuron stripe
        #pragma unroll
        for (int ks2 = 0; ks2 < 2; ++ks2) {
            #pragma unroll
            for (int t = 0; t < 4; ++t) {
                s16x8 Bf = *reinterpret_cast<const s16x8*>(
                    &hb[(16 * t + c) * HST2 + 32 * ks2 + 8 * g]);
                D[t] = __builtin_amdgcn_mfma_f32_16x16x32_bf16(w2f[2 * ms + ks2], Bf, D[t], 0, 0, 0);
            }
        }
    }

    // outputs 0..3 live on g==0 lanes: lane c holds sample q0+16t+c
    if (g == 0) {
        #pragma unroll
        for (int t = 0; t < 4; ++t) {
            int s = q0 + 16 * t + c;
            if (s < P) {
                uint2 w;
                w.x = pk2(D[t][0], D[t][1]);
                w.y = pk2(D[t][2], D[t][3]);
                preact[s] = w;
            }
        }
    }
}

// ===== Phase 2: per-ray composite (wave per ray) =====
__global__ __launch_bounds__(256) void k_comp(
    const float* __restrict__ rays_d, const float* __restrict__ intrs,
    const uint2* __restrict__ preact, const unsigned* __restrict__ packid,
    const int* __restrict__ cnt, const int* __restrict__ roff,
    const float* __restrict__ b2, float* __restrict__ out, int Bn, int N)
{
    int wid = threadIdx.x >> 6;
    int lane = threadIdx.x & 63;
    int b = blockIdx.x * 4 + wid;

    float* out_comp = out;
    float* out_alpha = out + (size_t)Bn * 3;

    int count = cnt[b];
    int poff = roff[b];

    float dx = rays_d[b * 3 + 0], dy = rays_d[b * 3 + 1], dz = rays_d[b * 3 + 2];
    float nrm = sqrtf(dx * dx + dy * dy + dz * dz);
    f32x4 b2v = *reinterpret_cast<const f32x4*>(b2);

    float T = 1.0f;
    float aR = 0.f, aG = 0.f, aB = 0.f, aA = 0.f;

    for (int r0 = 0; r0 < count; r0 += 64) {
        int r = r0 + lane;
        bool act = (r < count);
        int ri = poff + (act ? r : 0);
        uint2 pv = preact[ri];
        unsigned pos = packid[ri];
        int n = (int)(pos & 0xffffu);

        float p0 = bf2f(pv.x & 0xffffu) + b2v[0];
        float p1 = bf2f(pv.x >> 16)     + b2v[1];
        float p2 = bf2f(pv.y & 0xffffu) + b2v[2];
        float p3 = bf2f(pv.y >> 16)     + b2v[3];

        float density = fmaxf(p0, 0.0f);
        float dist = (intrs[(size_t)b * (N + 1) + n + 1] - intrs[(size_t)b * (N + 1) + n]) * nrm;
        float alpha = act ? (1.0f - expf(-density * dist)) : 0.0f;

        float fct = 1.0f - alpha + 1e-10f;
        float scan = fct;
        #pragma unroll
        for (int d = 1; d < 64; d <<= 1) {
            float o = __shfl_up(scan, d, 64);
            if (lane >= d) scan *= o;
        }
        float tot  = __shfl(scan, 63, 64);
        float excl = __shfl_up(scan, 1, 64);
        if (lane == 0) excl = 1.0f;

        float cum  = T * excl;
        float absl = alpha * cum;
        float sR = 1.0f / (1.0f + expf(-p1));
        float sG = 1.0f / (1.0f + expf(-p2));
        float sB = 1.0f / (1.0f + expf(-p3));
        aR = fmaf(absl, sR, aR);
        aG = fmaf(absl, sG, aG);
        aB = fmaf(absl, sB, aB);
        aA += absl;
        T *= tot;

        if (act) out_alpha[(size_t)b * N + n] = alpha;
    }

    #pragma unroll
    for (int d = 32; d > 0; d >>= 1) {
        aR += __shfl_down(aR, d, 64);
        aG += __shfl_down(aG, d, 64);
        aB += __shfl_down(aB, d, 64);
        aA += __shfl_down(aA, d, 64);
    }
    if (lane == 0) {
        out_comp[b * 3 + 0] = aR + (1.0f - aA);
        out_comp[b * 3 + 1] = aG + (1.0f - aA);
        out_comp[b * 3 + 2] = aB + (1.0f - aA);
    }
}

extern "C" void kernel_launch(void* const* d_in, const int* in_sizes, int n_in,
                              void* d_out, int out_size, void* d_ws, size_t ws_size,
                              hipStream_t stream) {
    const float* rays_d = (const float*)d_in[0];
    const float* intrs  = (const float*)d_in[1];
    const void*  maskp  = d_in[2];
    const float* data   = (const float*)d_in[3];
    const float* W1     = (const float*)d_in[4];
    const float* b1     = (const float*)d_in[5];
    const float* W2     = (const float*)d_in[6];
    const float* b2     = (const float*)d_in[7];
    float* out = (float*)d_out;

    int B = in_sizes[0] / 3;            // 8192
    int N = in_sizes[2] / B;            // 256
    int P = in_sizes[3] / DATA_DIM;     // packed sample count

    int* wsI        = (int*)d_ws;
    int* cnt        = wsI + 64;
    int* roff       = wsI + 64 + B;
    short* W1bf     = (short*)(wsI + 64 + 2 * B);         // 8 KB
    float* hpe      = (float*)(W1bf + WIDTH * 32);        // B*128 f32 = 4 MB
    unsigned* packid = (unsigned*)(hpe + (size_t)B * WIDTH);  // P u32
    uint2* preact   = (uint2*)(packid + ((P + 63) & ~63));    // P uint2

    float* out_alpha = out + (size_t)B * 3;

    k_zero<<<1, 1, 0, stream>>>(wsI);
    int nwords = (B * N) / 4;
    k_count_bytes<<<256, 256, 0, stream>>>((const unsigned int*)maskp, nwords, wsI);
    k_set_flag<<<1, 1, 0, stream>>>(wsI, P);
    k_ray_count<<<B, 64, 0, stream>>>(maskp, wsI + 1, cnt, N);
    k_scan<<<1, 1024, 0, stream>>>(cnt, roff, B);
    k_packid<<<B, 64, 0, stream>>>(maskp, wsI + 1, roff, packid, out_alpha, N);
    k_prep<<<(WIDTH * 32 + 255) / 256, 256, 0, stream>>>(W1, W1bf);
    k_hpe<<<256, 256, 0, stream>>>(rays_d, W1, b1, hpe, B);
    k_mlp<<<(P + 255) / 256, 256, 0, stream>>>(data, W1bf, W2, hpe, packid, preact, P);
    k_comp<<<B / 4, 256, 0, stream>>>(rays_d, intrs, preact, packid, cnt, roff, b2,
                                      out, B, N);
}

// Round 15
// 114.778 us; speedup vs baseline: 1.2960x; 1.0163x over previous
//
#include <hip/hip_runtime.h>
#include <hip/hip_bf16.h>
#include <math.h>

#define FREQS 9
#define DATA_DIM 28
#define WIDTH 128
#define IN_DIM 82
#define HST2 72      // shorts per sample row in 64-neuron H stripe (144 B) -> ~2-way
#define PEST 56      // f32 per W1_pe row in LDS (padded 54->56)

typedef float f32x4 __attribute__((ext_vector_type(4)));
typedef short s16x8 __attribute__((ext_vector_type(8)));

__device__ __forceinline__ short f2bf(float f) {
    unsigned u = __builtin_bit_cast(unsigned, f);
    u += 0x7fffu + ((u >> 16) & 1u);
    return (short)(u >> 16);
}

// native RNE pack -> v_cvt_pk_bf16_f32 (m240: don't hand-roll)
__device__ __forceinline__ unsigned pk2(float a, float b) {
    float2 t; t.x = a; t.y = b;
    __hip_bfloat162 h = __float22bfloat162_rn(t);
    unsigned r;
    __builtin_memcpy(&r, &h, sizeof(r));
    return r;
}

__device__ __forceinline__ float bf2f(unsigned u16v) {
    unsigned u = u16v << 16;
    return __builtin_bit_cast(float, u);
}

// coalesced global->LDS (16B/lane, lds dest = uniform base + lane*16)
__device__ __forceinline__ void gload_lds16(const void* g, void* l) {
    __builtin_amdgcn_global_load_lds(
        (const __attribute__((address_space(1))) unsigned int*)g,
        (__attribute__((address_space(3))) unsigned int*)l, 16, 0, 0);
}

// ws: [0] nz counter, [1] flag, [64..64+B) cnt, [64+B..64+2B) roff,
// W1bf 128*32 bf16 (8KB), hpe B*128 f32 (4MB), packid P u32, preact P uint2.
// NOTE (R13 lesson): packed order MUST be the reference's flatnonzero order
// (b-major exclusive scan) — data rows are indexed by it. No atomic packing.

__global__ void k_zero(int* ws) { ws[0] = 0; }

__global__ void k_count_bytes(const unsigned int* __restrict__ mw, int nwords, int* ws) {
    int tid = blockIdx.x * blockDim.x + threadIdx.x;
    int stride = gridDim.x * blockDim.x;
    int c = 0;
    for (int i = tid; i < nwords; i += stride) {
        unsigned int w = mw[i];
        c += ((w & 0xffu) != 0) + (((w >> 8) & 0xffu) != 0) +
             (((w >> 16) & 0xffu) != 0) + ((w >> 24) != 0);
    }
    __shared__ int red[256];
    red[threadIdx.x] = c;
    __syncthreads();
    for (int off = 128; off > 0; off >>= 1) {
        if (threadIdx.x < off) red[threadIdx.x] += red[threadIdx.x + off];
        __syncthreads();
    }
    if (threadIdx.x == 0) atomicAdd(&ws[0], red[0]);
}

__global__ void k_set_flag(int* ws, int P) { ws[1] = (ws[0] == P) ? 1 : 0; }

__global__ void k_ray_count(const void* __restrict__ maskp, const int* __restrict__ wsflag,
                            int* __restrict__ cnt, int N) {
    int b = blockIdx.x;
    int lane = threadIdx.x;
    int fl = wsflag[0];
    const unsigned char* m8 = (const unsigned char*)maskp;
    const int* m32 = (const int*)maskp;
    int base = 0;
    for (int t = 0; t < N / 64; ++t) {
        int n = t * 64 + lane;
        int mv = fl ? (int)m8[(size_t)b * N + n] : m32[(size_t)b * N + n];
        unsigned long long bal = __ballot(mv != 0);
        base += __popcll(bal);
    }
    if (lane == 0) cnt[b] = base;
}

__global__ void k_scan(const int* __restrict__ cnt, int* __restrict__ roff, int Bn) {
    __shared__ int sums[1024];
    int tid = threadIdx.x;
    int per = Bn / 1024;
    int loc[8];
    int s = 0;
    for (int i = 0; i < per; ++i) { loc[i] = s; s += cnt[tid * per + i]; }
    sums[tid] = s;
    __syncthreads();
    for (int off = 1; off < 1024; off <<= 1) {
        int t = sums[tid];
        int v = (tid >= off) ? sums[tid - off] : 0;
        __syncthreads();
        sums[tid] = t + v;
        __syncthreads();
    }
    int excl = sums[tid] - s;
    for (int i = 0; i < per; ++i) roff[tid * per + i] = excl + loc[i];
}

// packid[r] = (b<<16)|n for masked samples (ascending n); zero alpha for unmasked.
__global__ void k_packid(const void* __restrict__ maskp, const int* __restrict__ wsflag,
                         const int* __restrict__ roff, unsigned* __restrict__ packid,
                         float* __restrict__ out_alpha, int N) {
    int b = blockIdx.x;
    int lane = threadIdx.x;
    int fl = wsflag[0];
    const unsigned char* m8 = (const unsigned char*)maskp;
    const int* m32 = (const int*)maskp;
    int base = roff[b];
    for (int t = 0; t < N / 64; ++t) {
        int n = t * 64 + lane;
        int mv = fl ? (int)m8[(size_t)b * N + n] : m32[(size_t)b * N + n];
        bool m = (mv != 0);
        unsigned long long bal = __ballot(m);
        int rank = __popcll(bal & ((1ull << lane) - 1ull));
        if (m) packid[base + rank] = ((unsigned)b << 16) | (unsigned)n;
        else   out_alpha[(size_t)b * N + n] = 0.0f;
        base += __popcll(bal);
    }
}

// W1bf: data columns only (k=0..27), k=28..31 zero.
__global__ void k_prep(const float* __restrict__ W1, short* __restrict__ W1bf) {
    int tid = blockIdx.x * blockDim.x + threadIdx.x;
    if (tid < WIDTH * 32) {
        int n = tid / 32, k = tid - n * 32;
        W1bf[tid] = (k < DATA_DIM) ? f2bf(W1[n * IN_DIM + k]) : (short)0;
    }
}

// hpe[b][row] = b1[row] + sum_j W1[row][28+j] * pe_b[j]
__global__ __launch_bounds__(256) void k_hpe(
    const float* __restrict__ rays_d, const float* __restrict__ W1,
    const float* __restrict__ b1, float* __restrict__ hpe, int Bn)
{
    __shared__ __align__(16) float w1pe[WIDTH * PEST];   // 28 KB
    __shared__ __align__(16) float pe_s[4][PEST];

    int tid = threadIdx.x;
    for (int t = tid; t < WIDTH * PEST; t += 256) {
        int row = t / PEST, j = t - row * PEST;
        w1pe[t] = (j < 54) ? W1[row * IN_DIM + DATA_DIM + j] : 0.0f;
    }
    int wid = tid >> 6, lane = tid & 63;
    if (lane >= 54 && lane < PEST) pe_s[wid][lane] = 0.0f;
    __syncthreads();

    int raysPer = (Bn + gridDim.x - 1) / gridDim.x;
    for (int it = 0; it < raysPer; it += 4) {
        int b = blockIdx.x * raysPer + it + wid;
        if (b >= Bn) break;
        float dx = rays_d[b * 3 + 0], dy = rays_d[b * 3 + 1], dz = rays_d[b * 3 + 2];
        int idx = (lane < 54) ? lane : 0;
        int fb = idx / 6, t5 = idx - fb * 6;
        int ax = (t5 < 3) ? t5 : (t5 - 3);
        float dv = (ax == 0) ? dx : ((ax == 1) ? dy : dz);
        float ang = dv * (float)(1 << fb);
        float pev = (t5 < 3) ? sinf(ang) : cosf(ang);
        if (lane < 54) pe_s[wid][lane] = pev;

        #pragma unroll
        for (int rr = 0; rr < 2; ++rr) {
            int row = lane + 64 * rr;
            f32x4 s = {0.f, 0.f, 0.f, 0.f};
            #pragma unroll
            for (int j = 0; j < PEST; j += 4) {
                f32x4 wv = *reinterpret_cast<const f32x4*>(&w1pe[row * PEST + j]);
                f32x4 pv = *reinterpret_cast<const f32x4*>(&pe_s[wid][j]);
                s += wv * pv;
            }
            hpe[(size_t)b * WIDTH + row] = b1[row] + (s[0] + s[1]) + (s[2] + s[3]);
        }
    }
}

// ===== Phase 1: MLP over packed samples; coalesced LDS data staging =====
// (256,3): proven no-spill point (R10/R12/R14). R7/R11: anything tighter spills.
__global__ __launch_bounds__(256, 3) void k_mlp(
    const float* __restrict__ data, const short* __restrict__ W1bf,
    const float* __restrict__ W2, const float* __restrict__ hpe,
    const unsigned* __restrict__ packid, uint2* __restrict__ preact, int P)
{
    int wid = threadIdx.x >> 6;
    int lane = threadIdx.x & 63;
    int g = lane >> 4, c = lane & 15;

    // XCD-aware bijective swizzle (T1, m204): chunk grid across 8 XCDs for hpe L2 locality.
    int nwg = gridDim.x;
    int bid = blockIdx.x;
    if (nwg >= 8) {
        int q = nwg / 8, r = nwg % 8;
        int xcd = bid % 8, off = bid / 8;
        bid = (xcd < r ? xcd * (q + 1) : r * (q + 1) + (xcd - r) * q) + off;
    }
    int q0 = bid * 256 + wid * 64;

    __shared__ __align__(16) short hbuf[4][64 * HST2];   // 36.9 KB; per-wave 9216 B
    short* hb = &hbuf[wid][0];

    // packid loads (coalesced) — issue before staging to overlap
    unsigned bs[4];
    #pragma unroll
    for (int mb = 0; mb < 4; ++mb) {
        int s = q0 + 16 * mb + c;
        s = (s < P) ? s : (P - 1);
        bs[mb] = packid[s] >> 16;
    }

    // Coalesced stage of this wave's 64 data rows (7168 B) into the hbuf slice.
    // Per-lane global addr clamped in-bounds; garbage rows only feed s>=P samples
    // whose preact stores are guarded.
    {
        size_t maxoff = (size_t)P * 112 - 16;
        #pragma unroll
        for (int call = 0; call < 7; ++call) {
            size_t off = (size_t)q0 * 112 + (size_t)call * 1024 + (size_t)lane * 16;
            if (off > maxoff) off = maxoff;
            gload_lds16((const char*)data + off, (char*)hb + call * 1024);
        }
    }

    // W2 A-fragments (independent global loads — overlap with staging latency)
    s16x8 w2f[4];
    #pragma unroll
    for (int ks = 0; ks < 4; ++ks) {
        if (c < 4) {
            const float* wp = W2 + c * WIDTH + 32 * ks + 8 * g;
            f32x4 u = *reinterpret_cast<const f32x4*>(wp);
            f32x4 v = *reinterpret_cast<const f32x4*>(wp + 4);
            #pragma unroll
            for (int j = 0; j < 4; ++j) {
                w2f[ks][j] = f2bf(u[j]);
                w2f[ks][4 + j] = f2bf(v[j]);
            }
        } else {
            #pragma unroll
            for (int j = 0; j < 8; ++j) w2f[ks][j] = 0;
        }
    }

    asm volatile("s_waitcnt vmcnt(0)" ::: "memory");   // staged data visible in LDS

    // Build X B-fragments from LDS (2-way bank aliasing: free), then hbuf is reused.
    const float* hbf = reinterpret_cast<const float*>(hb);
    s16x8 a0[4];
    #pragma unroll
    for (int mb = 0; mb < 4; ++mb) {
        int row = 16 * mb + c;
        unsigned u0, u1, u2, u3;
        if (g < 3) {
            f32x4 lo = *reinterpret_cast<const f32x4*>(hbf + row * 28 + 8 * g);
            f32x4 hi = *reinterpret_cast<const f32x4*>(hbf + row * 28 + 8 * g + 4);
            u0 = pk2(lo[0], lo[1]); u1 = pk2(lo[2], lo[3]);
            u2 = pk2(hi[0], hi[1]); u3 = pk2(hi[2], hi[3]);
        } else {
            f32x4 lo = *reinterpret_cast<const f32x4*>(hbf + row * 28 + 24);
            u0 = pk2(lo[0], lo[1]); u1 = pk2(lo[2], lo[3]);
            u2 = 0; u3 = 0;
        }
        uint4 uu; uu.x = u0; uu.y = u1; uu.z = u2; uu.w = u3;
        a0[mb] = __builtin_bit_cast(s16x8, uu);
    }

    const s16x8* W1v = reinterpret_cast<const s16x8*>(W1bf);
    f32x4 D[4];
    #pragma unroll
    for (int t = 0; t < 4; ++t) D[t] = (f32x4){0.f, 0.f, 0.f, 0.f};

    #pragma unroll
    for (int ms = 0; ms < 2; ++ms) {
        // layer-1 for 64 neurons (4 nt iterations) -> H stripe cols 0..63
        #pragma unroll
        for (int hh = 0; hh < 4; ++hh) {
            int nt = 4 * ms + hh;
            s16x8 Bk0 = W1v[(16 * nt + c) * 4 + g];   // 8KB table, L1-resident

            f32x4 C0 = {0.f,0.f,0.f,0.f}, C1 = C0, C2 = C0, C3 = C0;
            C0 = __builtin_amdgcn_mfma_f32_16x16x32_bf16(Bk0, a0[0], C0, 0, 0, 0);
            C1 = __builtin_amdgcn_mfma_f32_16x16x32_bf16(Bk0, a0[1], C1, 0, 0, 0);
            C2 = __builtin_amdgcn_mfma_f32_16x16x32_bf16(Bk0, a0[2], C2, 0, 0, 0);
            C3 = __builtin_amdgcn_mfma_f32_16x16x32_bf16(Bk0, a0[3], C3, 0, 0, 0);

            f32x4 Cm[4] = {C0, C1, C2, C3};
            #pragma unroll
            for (int mb = 0; mb < 4; ++mb) {
                f32x4 hv = *reinterpret_cast<const f32x4*>(
                    hpe + (size_t)bs[mb] * WIDTH + 16 * nt + 4 * g);
                uint2 w;
                w.x = pk2(fmaxf(Cm[mb][0] + hv[0], 0.f), fmaxf(Cm[mb][1] + hv[1], 0.f));
                w.y = pk2(fmaxf(Cm[mb][2] + hv[2], 0.f), fmaxf(Cm[mb][3] + hv[3], 0.f));
                *reinterpret_cast<uint2*>(&hb[(16 * mb + c) * HST2 + 16 * hh + 4 * g]) = w;
            }
        }
        // single LDS turnaround, then 8 layer-2 MFMAs over the 64-neuron stripe
        #pragma unroll
        for (int ks2 = 0; ks2 < 2; ++ks2) {
            #pragma unroll
            for (int t = 0; t < 4; ++t) {
                s16x8 Bf = *reinterpret_cast<const s16x8*>(
                    &hb[(16 * t + c) * HST2 + 32 * ks2 + 8 * g]);
                D[t] = __builtin_amdgcn_mfma_f32_16x16x32_bf16(w2f[2 * ms + ks2], Bf, D[t], 0, 0, 0);
            }
        }
    }

    // outputs 0..3 live on g==0 lanes: lane c holds sample q0+16t+c
    if (g == 0) {
        #pragma unroll
        for (int t = 0; t < 4; ++t) {
            int s = q0 + 16 * t + c;
            if (s < P) {
                uint2 w;
                w.x = pk2(D[t][0], D[t][1]);
                w.y = pk2(D[t][2], D[t][3]);
                preact[s] = w;
            }
        }
    }
}

// ===== Phase 2: per-ray composite (wave per ray) =====
__global__ __launch_bounds__(256) void k_comp(
    const float* __restrict__ rays_d, const float* __restrict__ intrs,
    const uint2* __restrict__ preact, const unsigned* __restrict__ packid,
    const int* __restrict__ cnt, const int* __restrict__ roff,
    const float* __restrict__ b2, float* __restrict__ out, int Bn, int N)
{
    int wid = threadIdx.x >> 6;
    int lane = threadIdx.x & 63;
    int b = blockIdx.x * 4 + wid;

    float* out_comp = out;
    float* out_alpha = out + (size_t)Bn * 3;

    int count = cnt[b];
    int poff = roff[b];

    float dx = rays_d[b * 3 + 0], dy = rays_d[b * 3 + 1], dz = rays_d[b * 3 + 2];
    float nrm = sqrtf(dx * dx + dy * dy + dz * dz);
    f32x4 b2v = *reinterpret_cast<const f32x4*>(b2);

    float T = 1.0f;
    float aR = 0.f, aG = 0.f, aB = 0.f, aA = 0.f;

    for (int r0 = 0; r0 < count; r0 += 64) {
        int r = r0 + lane;
        bool act = (r < count);
        int ri = poff + (act ? r : 0);
        uint2 pv = preact[ri];
        unsigned pos = packid[ri];
        int n = (int)(pos & 0xffffu);

        float p0 = bf2f(pv.x & 0xffffu) + b2v[0];
        float p1 = bf2f(pv.x >> 16)     + b2v[1];
        float p2 = bf2f(pv.y & 0xffffu) + b2v[2];
        float p3 = bf2f(pv.y >> 16)     + b2v[3];

        float density = fmaxf(p0, 0.0f);
        float dist = (intrs[(size_t)b * (N + 1) + n + 1] - intrs[(size_t)b * (N + 1) + n]) * nrm;
        float alpha = act ? (1.0f - expf(-density * dist)) : 0.0f;

        float fct = 1.0f - alpha + 1e-10f;
        float scan = fct;
        #pragma unroll
        for (int d = 1; d < 64; d <<= 1) {
            float o = __shfl_up(scan, d, 64);
            if (lane >= d) scan *= o;
        }
        float tot  = __shfl(scan, 63, 64);
        float excl = __shfl_up(scan, 1, 64);
        if (lane == 0) excl = 1.0f;

        float cum  = T * excl;
        float absl = alpha * cum;
        float sR = 1.0f / (1.0f + expf(-p1));
        float sG = 1.0f / (1.0f + expf(-p2));
        float sB = 1.0f / (1.0f + expf(-p3));
        aR = fmaf(absl, sR, aR);
        aG = fmaf(absl, sG, aG);
        aB = fmaf(absl, sB, aB);
        aA += absl;
        T *= tot;

        if (act) out_alpha[(size_t)b * N + n] = alpha;
    }

    #pragma unroll
    for (int d = 32; d > 0; d >>= 1) {
        aR += __shfl_down(aR, d, 64);
        aG += __shfl_down(aG, d, 64);
        aB += __shfl_down(aB, d, 64);
        aA += __shfl_down(aA, d, 64);
    }
    if (lane == 0) {
        out_comp[b * 3 + 0] = aR + (1.0f - aA);
        out_comp[b * 3 + 1] = aG + (1.0f - aA);
        out_comp[b * 3 + 2] = aB + (1.0f - aA);
    }
}

extern "C" void kernel_launch(void* const* d_in, const int* in_sizes, int n_in,
                              void* d_out, int out_size, void* d_ws, size_t ws_size,
                              hipStream_t stream) {
    const float* rays_d = (const float*)d_in[0];
    const float* intrs  = (const float*)d_in[1];
    const void*  maskp  = d_in[2];
    const float* data   = (const float*)d_in[3];
    const float* W1     = (const float*)d_in[4];
    const float* b1     = (const float*)d_in[5];
    const float* W2     = (const float*)d_in[6];
    const float* b2     = (const float*)d_in[7];
    float* out = (float*)d_out;

    int B = in_sizes[0] / 3;            // 8192
    int N = in_sizes[2] / B;            // 256
    int P = in_sizes[3] / DATA_DIM;     // packed sample count

    int* wsI        = (int*)d_ws;
    int* cnt        = wsI + 64;
    int* roff       = wsI + 64 + B;
    short* W1bf     = (short*)(wsI + 64 + 2 * B);         // 8 KB
    float* hpe      = (float*)(W1bf + WIDTH * 32);        // B*128 f32 = 4 MB
    unsigned* packid = (unsigned*)(hpe + (size_t)B * WIDTH);  // P u32
    uint2* preact   = (uint2*)(packid + ((P + 63) & ~63));    // P uint2

    float* out_alpha = out + (size_t)B * 3;

    k_zero<<<1, 1, 0, stream>>>(wsI);
    int nwords = (B * N) / 4;
    k_count_bytes<<<256, 256, 0, stream>>>((const unsigned int*)maskp, nwords, wsI);
    k_set_flag<<<1, 1, 0, stream>>>(wsI, P);
    k_ray_count<<<B, 64, 0, stream>>>(maskp, wsI + 1, cnt, N);
    k_scan<<<1, 1024, 0, stream>>>(cnt, roff, B);
    k_packid<<<B, 64, 0, stream>>>(maskp, wsI + 1, roff, packid, out_alpha, N);
    k_prep<<<(WIDTH * 32 + 255) / 256, 256, 0, stream>>>(W1, W1bf);
    k_hpe<<<256, 256, 0, stream>>>(rays_d, W1, b1, hpe, B);
    k_mlp<<<(P + 255) / 256, 256, 0, stream>>>(data, W1bf, W2, hpe, packid, preact, P);
    k_comp<<<B / 4, 256, 0, stream>>>(rays_d, intrs, preact, packid, cnt, roff, b2,
                                      out, B, N);
}